// Round 3
// baseline (32.982 us; speedup 1.0000x reference)
//
#include <hip/hip_runtime.h>

#define KW   7
#define CIN  64
#define COUT 64
#define HH   64
#define WW   64
#define BB   4
#define HW   (HH * WW)

// ---------------------------------------------------------------------------
// Kernel 1: q / k / v 1x1-conv projections, interior only (padded positions
// of k_full/v_full are exactly 0 — synthesized as zeros in K2's staging).
// Block-uniform o-group -> weight reads scalarize; each x value feeds 12 FMAs.
// ---------------------------------------------------------------------------
__global__ __launch_bounds__(256) void qkv_kernel(
    const float* __restrict__ x,  const float* __restrict__ wq,
    const float* __restrict__ wk, const float* __restrict__ wv,
    float* __restrict__ qb, float* __restrict__ kb, float* __restrict__ vb)
{
    const int t  = threadIdx.x;
    const int b  = blockIdx.z;
    const int og = blockIdx.y * 4;
    const int p  = blockIdx.x * 256 + t;

    const float* xp  = x + (size_t)b * CIN * HW + p;
    const float* wqr = wq + og * CIN;
    const float* wkr = wk + og * CIN;
    const float* wvr = wv + og * CIN;

    float qa[4] = {0.f, 0.f, 0.f, 0.f};
    float ka[4] = {0.f, 0.f, 0.f, 0.f};
    float va[4] = {0.f, 0.f, 0.f, 0.f};

    #pragma unroll
    for (int c = 0; c < CIN; ++c) {
        const float xv = xp[(size_t)c * HW];
        #pragma unroll
        for (int oo = 0; oo < 4; ++oo) {
            qa[oo] = fmaf(xv, wqr[oo * CIN + c], qa[oo]);
            ka[oo] = fmaf(xv, wkr[oo * CIN + c], ka[oo]);
            va[oo] = fmaf(xv, wvr[oo * CIN + c], va[oo]);
        }
    }

    #pragma unroll
    for (int oo = 0; oo < 4; ++oo) {
        const size_t idx = ((size_t)b * COUT + og + oo) * HW + p;
        qb[idx] = qa[oo];
        kb[idx] = ka[oo];
        vb[idx] = va[oo];
    }
}

// ---------------------------------------------------------------------------
// Kernel 2: per-channel 7x7 local attention, register-blocked.
// Block (32,4)=128 threads covers a 16-row x 64-col tile of one (b,o) plane.
// Thread = 4 rows x 2 cols (8 outputs). The 10 window rows a thread needs are
// streamed once from LDS via aligned float2 (ds_read_b64): 12.5 b64/output
// instead of 98 b32/output. rel select (row vs col) hoisted via template;
// q*log2e*rel LUT precomputed in registers (static indices only).
// ---------------------------------------------------------------------------
#define TROWS 16
#define SROWS (TROWS + 6)
#define SCOLS 72   // 4 zero + 64 + 4 zero

template <bool USE_H>
__device__ __forceinline__ void attn_body(
    const float (*kt)[SCOLS], const float (*vt)[SCOLS],
    const float qs[4][2], const float at[4][2][KW],
    int tx, int ty, float s[4][2], float acc[4][2])
{
    #pragma unroll
    for (int rr = 0; rr < 10; ++rr) {
        const int srow = ty * 4 + rr;
        float kx[10], vx[10];
        #pragma unroll
        for (int s5 = 0; s5 < 5; ++s5) {
            *(float2*)&kx[2 * s5] = *(const float2*)&kt[srow][2 * tx + 2 * s5];
            *(float2*)&vx[2 * s5] = *(const float2*)&vt[srow][2 * tx + 2 * s5];
        }
        #pragma unroll
        for (int r = 0; r < 4; ++r) {
            const int i = rr - r;               // window row index
            if (i < 0 || i > 6) continue;       // compile-time pruned
            #pragma unroll
            for (int c = 0; c < 2; ++c) {
                const float q2 = qs[r][c];
                #pragma unroll
                for (int j = 0; j < KW; ++j) {
                    const float addt = USE_H ? at[r][c][i] : at[r][c][j];
                    const float e = __builtin_amdgcn_exp2f(
                        fmaf(q2, kx[c + 1 + j], addt));
                    s[r][c] += e;
                    acc[r][c] = fmaf(e, vx[c + 1 + j], acc[r][c]);
                }
            }
        }
    }
}

__global__ __launch_bounds__(128) void attn_kernel(
    const float* __restrict__ qb, const float* __restrict__ kb,
    const float* __restrict__ vb, const float* __restrict__ rel_h,
    const float* __restrict__ rel_w, float* __restrict__ out)
{
    __shared__ float kt[SROWS][SCOLS];
    __shared__ float vt[SROWS][SCOLS];

    const int tx  = threadIdx.x;              // 0..31  (column pair)
    const int ty  = threadIdx.y;              // 0..3   (4-row strip)
    const int tid = ty * 32 + tx;
    const int h0  = blockIdx.x * TROWS;
    const int o   = blockIdx.y;
    const int b   = blockIdx.z;
    const size_t plane = ((size_t)b * COUT + o) * HW;

    // Stage k/v rows h0-3 .. h0+18 with zero borders (replaces pad planes).
    for (int e = tid; e < SROWS * SCOLS; e += 128) {
        const int rr = e / SCOLS;
        const int lc = e - rr * SCOLS;
        const int gr = h0 - 3 + rr;
        const int gc = lc - 4;
        float kk = 0.f, vv = 0.f;
        if ((unsigned)gr < HH && (unsigned)gc < WW) {
            kk = kb[plane + (size_t)gr * WW + gc];
            vv = vb[plane + (size_t)gr * WW + gc];
        }
        kt[rr][lc] = kk;
        vt[rr][lc] = vv;
    }
    __syncthreads();

    const int c0    = tx * 2;
    const int hbase = h0 + ty * 4;

    float qs[4][2];
    #pragma unroll
    for (int r = 0; r < 4; ++r) {
        const float2 qv = *(const float2*)&qb[plane + (size_t)(hbase + r) * WW + c0];
        qs[r][0] = qv.x * 1.44269504088896f;   // fold log2(e)
        qs[r][1] = qv.y * 1.44269504088896f;
    }

    const bool use_h = (o < COUT / 2);         // block-uniform
    const float* rp = use_h ? (rel_h + o * KW) : (rel_w + (o - COUT / 2) * KW);
    float rel[KW];
    #pragma unroll
    for (int t = 0; t < KW; ++t) rel[t] = rp[t];

    float at[4][2][KW];
    #pragma unroll
    for (int r = 0; r < 4; ++r)
        #pragma unroll
        for (int c = 0; c < 2; ++c)
            #pragma unroll
            for (int t = 0; t < KW; ++t)
                at[r][c][t] = qs[r][c] * rel[t];

    float s[4][2]   = {{0.f, 0.f}, {0.f, 0.f}, {0.f, 0.f}, {0.f, 0.f}};
    float acc[4][2] = {{0.f, 0.f}, {0.f, 0.f}, {0.f, 0.f}, {0.f, 0.f}};

    if (use_h) attn_body<true >(kt, vt, qs, at, tx, ty, s, acc);
    else       attn_body<false>(kt, vt, qs, at, tx, ty, s, acc);

    #pragma unroll
    for (int r = 0; r < 4; ++r) {
        float2 ov;
        ov.x = acc[r][0] * __builtin_amdgcn_rcpf(s[r][0]);
        ov.y = acc[r][1] * __builtin_amdgcn_rcpf(s[r][1]);
        *(float2*)&out[plane + (size_t)(hbase + r) * WW + c0] = ov;
    }
}

extern "C" void kernel_launch(void* const* d_in, const int* in_sizes, int n_in,
                              void* d_out, int out_size, void* d_ws, size_t ws_size,
                              hipStream_t stream) {
    const float* x     = (const float*)d_in[0];
    const float* wq    = (const float*)d_in[1];
    const float* wk    = (const float*)d_in[2];
    const float* wv    = (const float*)d_in[3];
    const float* rel_h = (const float*)d_in[4];
    const float* rel_w = (const float*)d_in[5];
    float* out = (float*)d_out;

    float* qb = (float*)d_ws;
    float* kb = qb + (size_t)BB * COUT * HW;
    float* vb = kb + (size_t)BB * COUT * HW;

    dim3 g1(HW / 256, COUT / 4, BB);          // (16, 16, 4)
    qkv_kernel<<<g1, 256, 0, stream>>>(x, wq, wk, wv, qb, kb, vb);

    dim3 g2(HH / TROWS, COUT, BB);            // (4, 64, 4)
    dim3 b2(32, 4);
    attn_kernel<<<g2, b2, 0, stream>>>(qb, kb, vb, rel_h, rel_w, out);
}